// Round 16
// baseline (241.291 us; speedup 1.0000x reference)
//
#include <hip/hip_runtime.h>

#define TPTS 128          // control points T
#define MM   132          // T + DIM + 1
#define ST   136          // row stride in floats (34 float4)
#define NC4  34           // ST/4
#define NT   512          // fit threads (KB=12 needs 256-VGPR cap -> 8 waves)
#define KB   12           // panel width; 11 * 12 = 132 exactly, no remainder
#define NPAN 11
#define TEPS 1e-6f
#define HLN2 0.34657359027997264f   // 0.5*ln2 (folded into TPS weights)

__device__ __forceinline__ float rdlanef(float v, int l) {
    return __int_as_float(__builtin_amdgcn_readlane(__float_as_int(v), l));
}

// -------- Fit: no-pivot blocked LU, KB=12 (22 barrier-stages vs 34 @ KB=8) ----
// Phase 1 roles: [0,RB) row-TRSM | [128,128+ncols) strip-solve | [384,396) publish
// Phase 2 roles: [256,268) dsc->D+invd | all: trailing rank-12
__global__ __launch_bounds__(NT) void tps_fit(
    const float* __restrict__ pm,   // targets  [N][T][3]
    const float* __restrict__ pf,   // control  [N][T][3]
    const float* __restrict__ lmb,  // lambda   [N]
    float* __restrict__ theta)      // out [N][MM][3]; rows<T pre-scaled by 0.5*ln2
{
    extern __shared__ float smem[];
    float*  Mf   = smem;                        // [132][136]
    float4* M4   = reinterpret_cast<float4*>(smem);
    float*  invd = smem + MM*ST;                // [132]
    float*  sc   = invd + 132;                  // [128*3]
    float*  sg   = sc + TPTS*3;                 // [128*3]
    float*  dsc  = sg + TPTS*3;                 // [156] factored D scratch (16B-aligned)
    float4* dsc4 = reinterpret_cast<float4*>(dsc);

    const int n    = blockIdx.x;
    const int tid  = threadIdx.x;
    const int wid  = tid >> 6;
    const int lane = tid & 63;

    for (int i = tid; i < TPTS*3; i += NT) {
        sc[i] = pf[n*TPTS*3 + i];
        sg[i] = pm[n*TPTS*3 + i];
    }
    __syncthreads();
    const float lam = lmb[n];

    // ---- Fill augmented matrix; U(r) = 0.5*r2*ln(r2), r2 = d^2+EPS ----
    for (int q = tid; q < MM*NC4; q += NT) {
        const int row = q / NC4;
        const int cg  = q - row*NC4;
        float vv[4];
        #pragma unroll
        for (int e = 0; e < 4; ++e) {
            const int col = cg*4 + e;
            float v = 0.0f;
            if (col < TPTS) {
                if (row < TPTS) {
                    const float dx = sc[row*3+0] - sc[col*3+0];
                    const float dy = sc[row*3+1] - sc[col*3+1];
                    const float dz = sc[row*3+2] - sc[col*3+2];
                    const float r2 = fmaf(dx,dx, fmaf(dy,dy, fmaf(dz,dz, TEPS)));
                    v = 0.5f * r2 * __logf(r2);
                    if (row == col) v += lam;
                } else {
                    const int ci = row - TPTS;
                    v = (ci == 0) ? 1.0f : sc[col*3 + ci - 1];
                }
            } else if (col < MM) {
                if (row < TPTS) {
                    const int ci = col - TPTS;
                    v = (ci == 0) ? 1.0f : sc[row*3 + ci - 1];
                }
            } else if (col < MM + 3) {
                if (row < TPTS) v = sg[row*3 + (col - MM)];
            }
            vv[e] = v;
        }
        M4[q] = make_float4(vv[0], vv[1], vv[2], vv[3]);
    }
    __syncthreads();

    for (int p = 0; p < NPAN; ++p) {
        const int j0    = p*KB;
        const int cb    = j0 >> 2;              // 3 float4 groups per D row
        const int RB    = MM - (j0 + KB);       // rows below (120,108,...,0)
        const int ncols = 136 - (j0 + KB);      // strip cols incl RHS+pad (124..4)

        // ---- Phase 1 ----
        const bool needD = (tid < RB) || (tid >= 128 && tid < 128 + ncols)
                                      || (tid >= 384 && tid < 384 + KB);
        if (needD) {
            float d[KB][KB]; float rd[KB];
            #pragma unroll
            for (int m = 0; m < KB; ++m) {
                float4 a = M4[(j0+m)*NC4+cb], b = M4[(j0+m)*NC4+cb+1], c4 = M4[(j0+m)*NC4+cb+2];
                d[m][0]=a.x;  d[m][1]=a.y;  d[m][2]=a.z;  d[m][3]=a.w;
                d[m][4]=b.x;  d[m][5]=b.y;  d[m][6]=b.z;  d[m][7]=b.w;
                d[m][8]=c4.x; d[m][9]=c4.y; d[m][10]=c4.z; d[m][11]=c4.w;
            }
            #pragma unroll
            for (int k = 0; k < KB; ++k) {
                rd[k] = __builtin_amdgcn_rcpf(d[k][k]);
                #pragma unroll
                for (int i = 0; i < KB; ++i) {
                    if (i > k) {
                        const float l = d[i][k] * rd[k];
                        d[i][k] = l;
                        #pragma unroll
                        for (int c = 0; c < KB; ++c) { if (c > k) d[i][c] = fmaf(-l, d[k][c], d[i][c]); }
                    }
                }
            }
            if (tid < RB) {
                // row-TRSM of own row below the panel
                const int row = j0 + KB + tid;
                float4 a = M4[row*NC4+cb], b = M4[row*NC4+cb+1], c4 = M4[row*NC4+cb+2];
                const float av[KB] = {a.x,a.y,a.z,a.w,b.x,b.y,b.z,b.w,c4.x,c4.y,c4.z,c4.w};
                float l[KB];
                #pragma unroll
                for (int c = 0; c < KB; ++c) {
                    float v = av[c];
                    #pragma unroll
                    for (int k = 0; k < KB; ++k) { if (k < c) v = fmaf(-l[k], d[k][c], v); }
                    l[c] = v * rd[c];
                }
                M4[row*NC4+cb]   = make_float4(l[0],l[1],l[2],l[3]);
                M4[row*NC4+cb+1] = make_float4(l[4],l[5],l[6],l[7]);
                M4[row*NC4+cb+2] = make_float4(l[8],l[9],l[10],l[11]);
            } else if (tid >= 128 && tid < 128 + ncols) {
                // U-strip col forward-solve (unit-L part of d)
                const int col = j0 + KB + (tid - 128);
                float s[KB];
                #pragma unroll
                for (int m = 0; m < KB; ++m) s[m] = Mf[(j0+m)*ST + col];
                #pragma unroll
                for (int m = 1; m < KB; ++m) {
                    #pragma unroll
                    for (int k = 0; k < KB; ++k) { if (k < m) s[m] = fmaf(-d[m][k], s[k], s[m]); }
                }
                #pragma unroll
                for (int m = 0; m < KB; ++m) Mf[(j0+m)*ST + col] = s[m];
            } else {
                // publisher: thread m writes factored row m + rd[m] to dsc
                const int m = tid - 384;
                float rowv[KB]; float rdm = 1.0f;
                #pragma unroll
                for (int mm = 0; mm < KB; ++mm) {
                    #pragma unroll
                    for (int c = 0; c < KB; ++c) { if (mm == m) rowv[c] = d[mm][c]; }
                    if (mm == m) rdm = rd[mm];
                }
                dsc4[m*3+0] = make_float4(rowv[0],rowv[1],rowv[2],rowv[3]);
                dsc4[m*3+1] = make_float4(rowv[4],rowv[5],rowv[6],rowv[7]);
                dsc4[m*3+2] = make_float4(rowv[8],rowv[9],rowv[10],rowv[11]);
                dsc[KB*KB+m] = rdm;
            }
        }
        __syncthreads();

        // ---- Phase 2: dsc -> D-block + invd || trailing rank-12 ----
        if (tid >= 256 && tid < 256 + KB) {
            const int m = tid - 256;
            M4[(j0+m)*NC4+cb]   = dsc4[m*3+0];
            M4[(j0+m)*NC4+cb+1] = dsc4[m*3+1];
            M4[(j0+m)*NC4+cb+2] = dsc4[m*3+2];
            invd[j0+m] = dsc[KB*KB+m];
        }
        if (RB > 0) {
            const int cg0 = (j0 + KB) >> 2;
            const int ncg = NC4 - cg0;                   // 31,28,...,4 (p=0..9)
            const int tpc = NT / ncg;
            const int tcg = tid % ncg, trow = tid / ncg;
            if (trow < tpc) {
                const int cg = cg0 + tcg;
                float4 u[KB];
                #pragma unroll
                for (int m = 0; m < KB; ++m) u[m] = M4[(j0+m)*NC4 + cg];
                int i = j0 + KB + trow;
                for (; i + tpc < MM; i += 2*tpc) {
                    const int ib = i + tpc;
                    const float4 la0 = M4[i *NC4+cb], lb0 = M4[i *NC4+cb+1], lc0 = M4[i *NC4+cb+2];
                    const float4 la1 = M4[ib*NC4+cb], lb1 = M4[ib*NC4+cb+1], lc1 = M4[ib*NC4+cb+2];
                    float4 a0 = M4[i*NC4+cg], a1 = M4[ib*NC4+cg];
                    const float c0[KB] = {la0.x,la0.y,la0.z,la0.w,lb0.x,lb0.y,lb0.z,lb0.w,lc0.x,lc0.y,lc0.z,lc0.w};
                    const float c1[KB] = {la1.x,la1.y,la1.z,la1.w,lb1.x,lb1.y,lb1.z,lb1.w,lc1.x,lc1.y,lc1.z,lc1.w};
                    #pragma unroll
                    for (int m = 0; m < KB; ++m) {
                        a0.x = fmaf(-c0[m], u[m].x, a0.x); a0.y = fmaf(-c0[m], u[m].y, a0.y);
                        a0.z = fmaf(-c0[m], u[m].z, a0.z); a0.w = fmaf(-c0[m], u[m].w, a0.w);
                        a1.x = fmaf(-c1[m], u[m].x, a1.x); a1.y = fmaf(-c1[m], u[m].y, a1.y);
                        a1.z = fmaf(-c1[m], u[m].z, a1.z); a1.w = fmaf(-c1[m], u[m].w, a1.w);
                    }
                    M4[i *NC4+cg] = a0;
                    M4[ib*NC4+cg] = a1;
                }
                if (i < MM) {
                    const float4 la = M4[i*NC4+cb], lb = M4[i*NC4+cb+1], lc = M4[i*NC4+cb+2];
                    float4 a0 = M4[i*NC4+cg];
                    const float c0[KB] = {la.x,la.y,la.z,la.w,lb.x,lb.y,lb.z,lb.w,lc.x,lc.y,lc.z,lc.w};
                    #pragma unroll
                    for (int m = 0; m < KB; ++m) {
                        a0.x = fmaf(-c0[m], u[m].x, a0.x); a0.y = fmaf(-c0[m], u[m].y, a0.y);
                        a0.z = fmaf(-c0[m], u[m].z, a0.z); a0.w = fmaf(-c0[m], u[m].w, a0.w);
                    }
                    M4[i*NC4+cg] = a0;
                }
            }
        }
        __syncthreads();
    }

    // ---- Back-substitution (wave0), natural order, col-(j-1) prefetch ----
    if (wid == 0) {
        const int o0 = lane, o1 = lane + 64, o2 = lane + 128;
        float b0x,b0y,b0z, b1x,b1y,b1z, b2x=0,b2y=0,b2z=0;
        { float4 f = M4[o0*NC4 + 33]; b0x=f.x; b0y=f.y; b0z=f.z; }
        { float4 f = M4[o1*NC4 + 33]; b1x=f.x; b1y=f.y; b1z=f.z; }
        if (o2 < MM) { float4 f = M4[o2*NC4 + 33]; b2x=f.x; b2y=f.y; b2z=f.z; }
        float uc0 = Mf[o0*ST + (MM-1)];
        float uc1 = Mf[o1*ST + (MM-1)];
        float uc2 = (o2 < MM) ? Mf[o2*ST + (MM-1)] : 0.0f;
        float dvc = invd[MM-1];
        for (int j = MM - 1; j >= 0; --j) {
            float un0 = 0.f, un1 = 0.f, un2 = 0.f, dvn = 0.f;
            if (j > 0) {
                un0 = Mf[o0*ST + j-1];
                un1 = Mf[o1*ST + j-1];
                un2 = (o2 < MM) ? Mf[o2*ST + j-1] : 0.0f;
                dvn = invd[j-1];
            }
            const int jr = j >> 6, jl = j & 63;
            float s0, s1, s2;
            if (jr == 0)      { s0 = b0x; s1 = b0y; s2 = b0z; }
            else if (jr == 1) { s0 = b1x; s1 = b1y; s2 = b1z; }
            else              { s0 = b2x; s1 = b2y; s2 = b2z; }
            const float x0 = rdlanef(s0, jl) * dvc;
            const float x1 = rdlanef(s1, jl) * dvc;
            const float x2 = rdlanef(s2, jl) * dvc;
            if (o0 < j) { b0x = fmaf(-uc0,x0,b0x); b0y = fmaf(-uc0,x1,b0y); b0z = fmaf(-uc0,x2,b0z); }
            if (o1 < j) { b1x = fmaf(-uc1,x0,b1x); b1y = fmaf(-uc1,x1,b1y); b1z = fmaf(-uc1,x2,b1z); }
            if (o2 < j && o2 < MM) { b2x = fmaf(-uc2,x0,b2x); b2y = fmaf(-uc2,x1,b2y); b2z = fmaf(-uc2,x2,b2z); }
            if (lane == jl) {
                const float scale = (j < TPTS) ? HLN2 : 1.0f;
                theta[n*MM*3 + j*3 + 0] = x0 * scale;
                theta[n*MM*3 + j*3 + 1] = x1 * scale;
                theta[n*MM*3 + j*3 + 2] = x2 * scale;
            }
            uc0 = un0; uc1 = un1; uc2 = un2; dvc = dvn;
        }
    }
}

// ------- Eval: 2 grid points (adjacent in W) per thread (measured-best, R14) ------
__global__ __launch_bounds__(256) void tps_eval(
    const float* __restrict__ pf,
    const float* __restrict__ theta,
    float* __restrict__ out)
{
    const int b   = blockIdx.x;
    const int n   = b >> 9;                          // 512 blocks per batch
    const int pp  = ((b & 511) << 8) | threadIdx.x;  // per-batch point-pair index
    const int g0  = pp << 1;                         // even point: w0 = g0&63 <= 62
    const int d   = g0 >> 12;
    const int h   = (g0 >> 6) & 63;
    const int w   = g0 & 63;
    const float stepv = 2.0f / 63.0f;
    const float gx0 = fmaf((float)w,       stepv, -1.0f);
    const float gx1 = fmaf((float)(w + 1), stepv, -1.0f);
    const float gy  = fmaf((float)h, stepv, -1.0f);
    const float gz  = fmaf((float)d, stepv, -1.0f);

    const float* __restrict__ c  = pf    + n * TPTS * 3;
    const float* __restrict__ th = theta + n * MM * 3;

    float p0x = 0.f, p0y = 0.f, p0z = 0.f;
    float p1x = 0.f, p1y = 0.f, p1z = 0.f;
    #pragma unroll 8
    for (int t = 0; t < TPTS; ++t) {
        const float cx = c[t*3+0], cy = c[t*3+1], cz = c[t*3+2];
        const float dy = gy - cy;
        const float dz = gz - cz;
        const float s  = fmaf(dy,dy, fmaf(dz,dz, TEPS));   // shared partial r2
        const float dx0 = gx0 - cx;
        const float dx1 = gx1 - cx;
        const float r20 = fmaf(dx0,dx0, s);
        const float r21 = fmaf(dx1,dx1, s);
        const float u0  = r20 * __log2f(r20);              // 0.5*ln2 folded into w
        const float u1  = r21 * __log2f(r21);
        const float t0 = th[t*3+0], t1 = th[t*3+1], t2 = th[t*3+2];
        p0x = fmaf(u0, t0, p0x); p0y = fmaf(u0, t1, p0y); p0z = fmaf(u0, t2, p0z);
        p1x = fmaf(u1, t0, p1x); p1y = fmaf(u1, t1, p1y); p1z = fmaf(u1, t2, p1z);
    }
    const float* aa = th + TPTS*3;
    const float b0 = fmaf(gy, aa[6], fmaf(gz, aa[9],  aa[0]));
    const float b1 = fmaf(gy, aa[7], fmaf(gz, aa[10], aa[1]));
    const float b2 = fmaf(gy, aa[8], fmaf(gz, aa[11], aa[2]));
    p0x = fmaf(gx0, aa[3], p0x + b0);
    p0y = fmaf(gx0, aa[4], p0y + b1);
    p0z = fmaf(gx0, aa[5], p0z + b2);
    p1x = fmaf(gx1, aa[3], p1x + b0);
    p1y = fmaf(gx1, aa[4], p1y + b1);
    p1z = fmaf(gx1, aa[5], p1z + b2);

    float2* o2 = reinterpret_cast<float2*>(out + ((size_t)n * 262144 + g0) * 3);
    o2[0] = make_float2(p0x, p0y);
    o2[1] = make_float2(p0z, p1x);
    o2[2] = make_float2(p1y, p1z);
}

extern "C" void kernel_launch(void* const* d_in, const int* in_sizes, int n_in,
                              void* d_out, int out_size, void* d_ws, size_t ws_size,
                              hipStream_t stream) {
    (void)n_in; (void)out_size; (void)ws_size;
    const float* pm = (const float*)d_in[0];
    const float* pf = (const float*)d_in[1];
    const float* lm = (const float*)d_in[2];
    float* outp  = (float*)d_out;
    float* theta = (float*)d_ws;

    const int N = in_sizes[2];
    // Mf 17952 + invd 132 + sc 384 + sg 384 + dsc 156 = 19008 floats = 76,032 B
    const size_t lds = (size_t)(MM*ST + 132 + TPTS*3*2 + KB*KB + KB) * sizeof(float);

    (void)hipFuncSetAttribute(reinterpret_cast<const void*>(tps_fit),
                              hipFuncAttributeMaxDynamicSharedMemorySize, (int)lds);

    tps_fit<<<N, NT, lds, stream>>>(pm, pf, lm, theta);
    tps_eval<<<N * 512, 256, 0, stream>>>(pf, theta, outp);
}

// Round 17
// 91.518 us; speedup vs baseline: 2.6365x; 2.6365x over previous
//
#include <hip/hip_runtime.h>

#define TPTS 128          // control points T
#define MM   132          // T + DIM + 1
#define ST   136          // row stride in floats (34 float4)
#define NC4  34           // ST/4
#define NT   1024         // fit block threads (16 waves -> 4 waves/SIMD TLP)
#define NPAN 17
#define TEPS 1e-6f
#define HLN2 0.34657359027997264f   // 0.5*ln2 (folded into TPS weights)

__device__ __forceinline__ float rdlanef(float v, int l) {
    return __int_as_float(__builtin_amdgcn_readlane(__float_as_int(v), l));
}

// -------- Fit: blocked LU, NO pivoting -> fully data-parallel panels --------
// (measured-best structure: R9 phases + NT=1024 TLP; KB=8 is the spill-safe max)
__global__ __launch_bounds__(NT) void tps_fit(
    const float* __restrict__ pm,   // targets  [N][T][3]
    const float* __restrict__ pf,   // control  [N][T][3]
    const float* __restrict__ lmb,  // lambda   [N]
    float* __restrict__ theta)      // out [N][MM][3]; rows<T pre-scaled by 0.5*ln2
{
    extern __shared__ float smem[];
    float*  Mf   = smem;                        // [132][136]
    float4* M4   = reinterpret_cast<float4*>(smem);
    float*  invd = smem + MM*ST;                // [132]
    float*  sc   = invd + 132;                  // [128*3]
    float*  sg   = sc + TPTS*3;                 // [128*3]
    float*  dsc  = sg + TPTS*3;                 // [72] factored D scratch
    float4* dsc4 = reinterpret_cast<float4*>(dsc);

    const int n    = blockIdx.x;
    const int tid  = threadIdx.x;
    const int wid  = tid >> 6;
    const int lane = tid & 63;

    for (int i = tid; i < TPTS*3; i += NT) {
        sc[i] = pf[n*TPTS*3 + i];
        sg[i] = pm[n*TPTS*3 + i];
    }
    __syncthreads();
    const float lam = lmb[n];

    // ---- Fill augmented matrix; U(r) = 0.5*r2*ln(r2), r2 = d^2+EPS ----
    for (int q = tid; q < MM*NC4; q += NT) {
        const int row = q / NC4;
        const int cg  = q - row*NC4;
        float vv[4];
        #pragma unroll
        for (int e = 0; e < 4; ++e) {
            const int col = cg*4 + e;
            float v = 0.0f;
            if (col < TPTS) {
                if (row < TPTS) {
                    const float dx = sc[row*3+0] - sc[col*3+0];
                    const float dy = sc[row*3+1] - sc[col*3+1];
                    const float dz = sc[row*3+2] - sc[col*3+2];
                    const float r2 = fmaf(dx,dx, fmaf(dy,dy, fmaf(dz,dz, TEPS)));
                    v = 0.5f * r2 * __logf(r2);
                    if (row == col) v += lam;
                } else {
                    const int ci = row - TPTS;
                    v = (ci == 0) ? 1.0f : sc[col*3 + ci - 1];
                }
            } else if (col < MM) {
                if (row < TPTS) {
                    const int ci = col - TPTS;
                    v = (ci == 0) ? 1.0f : sc[row*3 + ci - 1];
                }
            } else if (col < MM + 3) {
                if (row < TPTS) v = sg[row*3 + (col - MM)];
            }
            vv[e] = v;
        }
        M4[q] = make_float4(vv[0], vv[1], vv[2], vv[3]);
    }
    __syncthreads();

    for (int p = 0; p < NPAN; ++p) {
        const int j0    = p*8;
        const int kb    = (MM - j0 >= 8) ? 8 : (MM - j0);       // 8; last panel 4
        const int cb    = j0 >> 2;
        const int RB    = (MM > j0 + 8) ? (MM - (j0 + 8)) : 0;  // rows below
        const int ncols = 136 - (j0 + 8);                       // strip cols (0 @ p=16)

        // ---- Phase 1 ----
        const bool needD = (tid < RB) || (tid >= 128 && tid < 128 + ncols)
                                      || (tid >= 384 && tid < 392);
        if (needD) {
            float d[8][8]; float rd[8];
            #pragma unroll
            for (int m = 0; m < 8; ++m) {
                if (m < kb) {
                    float4 a = M4[(j0+m)*NC4+cb], b = M4[(j0+m)*NC4+cb+1];
                    d[m][0]=a.x; d[m][1]=a.y; d[m][2]=a.z; d[m][3]=a.w;
                    d[m][4]=b.x; d[m][5]=b.y; d[m][6]=b.z; d[m][7]=b.w;
                } else {
                    #pragma unroll
                    for (int c = 0; c < 8; ++c) d[m][c] = 0.0f;
                }
            }
            #pragma unroll
            for (int k = 0; k < 8; ++k) {
                if (k < kb) {
                    rd[k] = __builtin_amdgcn_rcpf(d[k][k]);
                    #pragma unroll
                    for (int i = 0; i < 8; ++i) {
                        if (i > k && i < kb) {
                            const float l = d[i][k] * rd[k];
                            d[i][k] = l;
                            #pragma unroll
                            for (int c = 0; c < 8; ++c) { if (c > k) d[i][c] = fmaf(-l, d[k][c], d[i][c]); }
                        }
                    }
                } else {
                    rd[k] = 1.0f;
                }
            }
            if (tid < RB) {
                const int row = j0 + 8 + tid;
                float4 a = M4[row*NC4+cb], b = M4[row*NC4+cb+1];
                float av[8] = {a.x,a.y,a.z,a.w,b.x,b.y,b.z,b.w};
                float l[8];
                #pragma unroll
                for (int c = 0; c < 8; ++c) {
                    float v = av[c];
                    #pragma unroll
                    for (int k = 0; k < 8; ++k) { if (k < c) v = fmaf(-l[k], d[k][c], v); }
                    l[c] = v * rd[c];
                }
                M4[row*NC4+cb]   = make_float4(l[0],l[1],l[2],l[3]);
                M4[row*NC4+cb+1] = make_float4(l[4],l[5],l[6],l[7]);
            } else if (tid >= 128 && tid < 128 + ncols) {
                const int col = j0 + 8 + (tid - 128);
                float s[8];
                #pragma unroll
                for (int m = 0; m < 8; ++m) s[m] = Mf[(j0+m)*ST + col];
                #pragma unroll
                for (int m = 1; m < 8; ++m) {
                    #pragma unroll
                    for (int k = 0; k < 8; ++k) { if (k < m) s[m] = fmaf(-d[m][k], s[k], s[m]); }
                }
                #pragma unroll
                for (int m = 0; m < 8; ++m) Mf[(j0+m)*ST + col] = s[m];
            } else {
                const int m = tid - 384;
                float rowv[8];
                #pragma unroll
                for (int mm = 0; mm < 8; ++mm) {
                    #pragma unroll
                    for (int c = 0; c < 8; ++c) { if (mm == m) rowv[c] = d[mm][c]; }
                }
                float rdm = 1.0f;
                #pragma unroll
                for (int mm = 0; mm < 8; ++mm) { if (mm == m) rdm = rd[mm]; }
                dsc4[m*2+0] = make_float4(rowv[0],rowv[1],rowv[2],rowv[3]);
                dsc4[m*2+1] = make_float4(rowv[4],rowv[5],rowv[6],rowv[7]);
                dsc[64+m]   = rdm;
            }
        }
        __syncthreads();

        // ---- Phase 2: dsc -> D-block + invd || trailing rank-8 ----
        if (tid >= 256 && tid < 264) {
            const int m = tid - 256;
            if (m < kb) {
                M4[(j0+m)*NC4+cb]   = dsc4[m*2+0];
                M4[(j0+m)*NC4+cb+1] = dsc4[m*2+1];
                invd[j0+m] = dsc[64+m];
            }
        }
        if (RB > 0) {
            const int cg0 = (j0 + 8) >> 2;
            const int ncg = NC4 - cg0;                   // 32,30,...,2
            const int tpc = NT / ncg;
            const int tcg = tid % ncg, trow = tid / ncg;
            if (trow < tpc) {
                const int cg = cg0 + tcg;
                float4 u[8];
                #pragma unroll
                for (int m = 0; m < 8; ++m) u[m] = M4[(j0+m)*NC4 + cg];
                int i = j0 + 8 + trow;
                for (; i + tpc < MM; i += 2*tpc) {
                    const int ib = i + tpc;
                    const float4 la0 = M4[i *NC4+cb], lb0 = M4[i *NC4+cb+1];
                    const float4 la1 = M4[ib*NC4+cb], lb1 = M4[ib*NC4+cb+1];
                    float4 a0 = M4[i*NC4+cg], a1 = M4[ib*NC4+cg];
                    const float c0[8] = {la0.x,la0.y,la0.z,la0.w,lb0.x,lb0.y,lb0.z,lb0.w};
                    const float c1[8] = {la1.x,la1.y,la1.z,la1.w,lb1.x,lb1.y,lb1.z,lb1.w};
                    #pragma unroll
                    for (int m = 0; m < 8; ++m) {
                        a0.x = fmaf(-c0[m], u[m].x, a0.x); a0.y = fmaf(-c0[m], u[m].y, a0.y);
                        a0.z = fmaf(-c0[m], u[m].z, a0.z); a0.w = fmaf(-c0[m], u[m].w, a0.w);
                        a1.x = fmaf(-c1[m], u[m].x, a1.x); a1.y = fmaf(-c1[m], u[m].y, a1.y);
                        a1.z = fmaf(-c1[m], u[m].z, a1.z); a1.w = fmaf(-c1[m], u[m].w, a1.w);
                    }
                    M4[i *NC4+cg] = a0;
                    M4[ib*NC4+cg] = a1;
                }
                if (i < MM) {
                    const float4 la = M4[i*NC4+cb], lb = M4[i*NC4+cb+1];
                    float4 a0 = M4[i*NC4+cg];
                    const float c0[8] = {la.x,la.y,la.z,la.w,lb.x,lb.y,lb.z,lb.w};
                    #pragma unroll
                    for (int m = 0; m < 8; ++m) {
                        a0.x = fmaf(-c0[m], u[m].x, a0.x); a0.y = fmaf(-c0[m], u[m].y, a0.y);
                        a0.z = fmaf(-c0[m], u[m].z, a0.z); a0.w = fmaf(-c0[m], u[m].w, a0.w);
                    }
                    M4[i*NC4+cg] = a0;
                }
            }
        }
        __syncthreads();
    }

    // ---- Back-substitution (wave0), natural order, col-(j-1) prefetch ----
    if (wid == 0) {
        const int o0 = lane, o1 = lane + 64, o2 = lane + 128;
        float b0x,b0y,b0z, b1x,b1y,b1z, b2x=0,b2y=0,b2z=0;
        { float4 f = M4[o0*NC4 + 33]; b0x=f.x; b0y=f.y; b0z=f.z; }
        { float4 f = M4[o1*NC4 + 33]; b1x=f.x; b1y=f.y; b1z=f.z; }
        if (o2 < MM) { float4 f = M4[o2*NC4 + 33]; b2x=f.x; b2y=f.y; b2z=f.z; }
        float uc0 = Mf[o0*ST + (MM-1)];
        float uc1 = Mf[o1*ST + (MM-1)];
        float uc2 = (o2 < MM) ? Mf[o2*ST + (MM-1)] : 0.0f;
        float dvc = invd[MM-1];
        for (int j = MM - 1; j >= 0; --j) {
            float un0 = 0.f, un1 = 0.f, un2 = 0.f, dvn = 0.f;
            if (j > 0) {
                un0 = Mf[o0*ST + j-1];
                un1 = Mf[o1*ST + j-1];
                un2 = (o2 < MM) ? Mf[o2*ST + j-1] : 0.0f;
                dvn = invd[j-1];
            }
            const int jr = j >> 6, jl = j & 63;
            float s0, s1, s2;
            if (jr == 0)      { s0 = b0x; s1 = b0y; s2 = b0z; }
            else if (jr == 1) { s0 = b1x; s1 = b1y; s2 = b1z; }
            else              { s0 = b2x; s1 = b2y; s2 = b2z; }
            const float x0 = rdlanef(s0, jl) * dvc;
            const float x1 = rdlanef(s1, jl) * dvc;
            const float x2 = rdlanef(s2, jl) * dvc;
            if (o0 < j) { b0x = fmaf(-uc0,x0,b0x); b0y = fmaf(-uc0,x1,b0y); b0z = fmaf(-uc0,x2,b0z); }
            if (o1 < j) { b1x = fmaf(-uc1,x0,b1x); b1y = fmaf(-uc1,x1,b1y); b1z = fmaf(-uc1,x2,b1z); }
            if (o2 < j && o2 < MM) { b2x = fmaf(-uc2,x0,b2x); b2y = fmaf(-uc2,x1,b2y); b2z = fmaf(-uc2,x2,b2z); }
            if (lane == jl) {
                const float scale = (j < TPTS) ? HLN2 : 1.0f;
                theta[n*MM*3 + j*3 + 0] = x0 * scale;
                theta[n*MM*3 + j*3 + 1] = x1 * scale;
                theta[n*MM*3 + j*3 + 2] = x2 * scale;
            }
            uc0 = un0; uc1 = un1; uc2 = un2; dvc = dvn;
        }
    }
}

// ------- Eval: 2 grid points (adjacent in W) per thread; shared dy/dz term -------
__global__ __launch_bounds__(256) void tps_eval(
    const float* __restrict__ pf,
    const float* __restrict__ theta,
    float* __restrict__ out)
{
    const int b   = blockIdx.x;
    const int n   = b >> 9;                          // 512 blocks per batch
    const int pp  = ((b & 511) << 8) | threadIdx.x;  // per-batch point-pair index
    const int g0  = pp << 1;                         // even point: w0 = g0&63 <= 62
    const int d   = g0 >> 12;
    const int h   = (g0 >> 6) & 63;
    const int w   = g0 & 63;
    const float stepv = 2.0f / 63.0f;
    const float gx0 = fmaf((float)w,       stepv, -1.0f);
    const float gx1 = fmaf((float)(w + 1), stepv, -1.0f);
    const float gy  = fmaf((float)h, stepv, -1.0f);
    const float gz  = fmaf((float)d, stepv, -1.0f);

    const float* __restrict__ c  = pf    + n * TPTS * 3;
    const float* __restrict__ th = theta + n * MM * 3;

    float p0x = 0.f, p0y = 0.f, p0z = 0.f;
    float p1x = 0.f, p1y = 0.f, p1z = 0.f;
    #pragma unroll 8
    for (int t = 0; t < TPTS; ++t) {
        const float cx = c[t*3+0], cy = c[t*3+1], cz = c[t*3+2];
        const float dy = gy - cy;
        const float dz = gz - cz;
        const float s  = fmaf(dy,dy, fmaf(dz,dz, TEPS));   // shared partial r2
        const float dx0 = gx0 - cx;
        const float dx1 = gx1 - cx;
        const float r20 = fmaf(dx0,dx0, s);
        const float r21 = fmaf(dx1,dx1, s);
        const float u0  = r20 * __log2f(r20);              // 0.5*ln2 folded into w
        const float u1  = r21 * __log2f(r21);
        const float t0 = th[t*3+0], t1 = th[t*3+1], t2 = th[t*3+2];
        p0x = fmaf(u0, t0, p0x); p0y = fmaf(u0, t1, p0y); p0z = fmaf(u0, t2, p0z);
        p1x = fmaf(u1, t0, p1x); p1y = fmaf(u1, t1, p1y); p1z = fmaf(u1, t2, p1z);
    }
    const float* aa = th + TPTS*3;
    const float b0 = fmaf(gy, aa[6], fmaf(gz, aa[9],  aa[0]));
    const float b1 = fmaf(gy, aa[7], fmaf(gz, aa[10], aa[1]));
    const float b2 = fmaf(gy, aa[8], fmaf(gz, aa[11], aa[2]));
    p0x = fmaf(gx0, aa[3], p0x + b0);
    p0y = fmaf(gx0, aa[4], p0y + b1);
    p0z = fmaf(gx0, aa[5], p0z + b2);
    p1x = fmaf(gx1, aa[3], p1x + b0);
    p1y = fmaf(gx1, aa[4], p1y + b1);
    p1z = fmaf(gx1, aa[5], p1z + b2);

    float2* o2 = reinterpret_cast<float2*>(out + ((size_t)n * 262144 + g0) * 3);
    o2[0] = make_float2(p0x, p0y);
    o2[1] = make_float2(p0z, p1x);
    o2[2] = make_float2(p1y, p1z);
}

extern "C" void kernel_launch(void* const* d_in, const int* in_sizes, int n_in,
                              void* d_out, int out_size, void* d_ws, size_t ws_size,
                              hipStream_t stream) {
    (void)n_in; (void)out_size; (void)ws_size;
    const float* pm = (const float*)d_in[0];
    const float* pf = (const float*)d_in[1];
    const float* lm = (const float*)d_in[2];
    float* outp  = (float*)d_out;
    float* theta = (float*)d_ws;

    const int N = in_sizes[2];
    // Mf 17952 + invd 132 + sc 384 + sg 384 + dsc 72 = 18924 floats = 75,696 B
    const size_t lds = (size_t)(MM*ST + 132 + TPTS*3*2 + 72) * sizeof(float);

    (void)hipFuncSetAttribute(reinterpret_cast<const void*>(tps_fit),
                              hipFuncAttributeMaxDynamicSharedMemorySize, (int)lds);

    tps_fit<<<N, NT, lds, stream>>>(pm, pf, lm, theta);
    tps_eval<<<N * 512, 256, 0, stream>>>(pf, theta, outp);
}